// Round 17
// baseline (176.749 us; speedup 1.0000x reference)
//
#include <hip/hip_runtime.h>
#include <math.h>

#define NBINS 255
#define BIN_LO_F (-20.0f)
#define BIN_HI_F (20.0f)

typedef __attribute__((ext_vector_type(8))) short short8;
typedef __attribute__((ext_vector_type(16))) float f32x16;

__device__ __forceinline__ unsigned short f2bf(float f) {
    unsigned u = __builtin_bit_cast(unsigned, f);
    unsigned r = u + 0x7fffu + ((u >> 16) & 1u);
    return (unsigned short)(r >> 16);
}

__device__ __forceinline__ unsigned pkbf(float lo, float hi) {
    unsigned d;
    asm("v_cvt_pk_bf16_f32 %0, %1, %2" : "=v"(d) : "v"(lo), "v"(hi));
    return d;
}

__device__ __forceinline__ short8 mk8(unsigned a, unsigned b, unsigned c, unsigned d) {
    union { unsigned u[4]; short8 s; } t;
    t.u[0] = a; t.u[1] = b; t.u[2] = c; t.u[3] = d;
    return t.s;
}

__device__ __forceinline__ void glds16(const void* g, void* l) {
    __builtin_amdgcn_global_load_lds(
        (const __attribute__((address_space(1))) unsigned int*)g,
        (__attribute__((address_space(3))) unsigned int*)l, 16, 0, 0);
}

__device__ __forceinline__ double wave_reduce_sum_d(double v) {
    #pragma unroll
    for (int m = 32; m >= 1; m >>= 1) v += __shfl_xor(v, m, 64);
    return v;
}

// Pack W (D,255) fp32 -> bf16 image, one 16 KB block per K-step of 32:
// 16B unit u: kt=u>>10, v=u&1023: ks=v>>9, lh=(v>>8)&1, col=v&255.
// elem e: k = kt*32 + ks*16 + lh*8 + e, column col (255 -> zero pad).
// GEMM B-frag read (ks,lhi,colgroup) is linear 16B/lane -> conflict-free.
__global__ __launch_bounds__(256) void pack_w7(
    const float* __restrict__ W, char* __restrict__ Wimg)
{
    int u = blockIdx.x * 256 + threadIdx.x;
    int kt = u >> 10;
    int v  = u & 1023;
    int ks = v >> 9;
    int lh = (v >> 8) & 1;
    int col = v & 255;
    int k0  = kt * 32 + ks * 16 + lh * 8;
    short8 s;
    #pragma unroll
    for (int e = 0; e < 8; ++e)
        s[e] = (col < NBINS) ? (short)f2bf(W[(size_t)(k0 + e) * NBINS + col]) : (short)0;
    *(short8*)(Wimg + (size_t)u * 16) = s;
}

// v17 = v16 with the B-staging offset bug fixed (+8192 -> +1024; the per-wave B slice
// is 2 x 1 KB contiguous at wave*2048). Fat-phase geometry + counted-vmcnt dbuf:
// BM=128 x BN=256 x BK=32, split-4 -> grid 544 (2 blocks/CU via 64 KB LDS, 16 waves/CU).
// 512 thr = 8 waves (2M x 4N), wave tile 64x64, acc 2x2 f32x16.
// A: fp32 LDS 16 KB/buf, full-line glds (8 rows x 128B per instr), 16B-unit XOR
//    u^(row&7) on BOTH sides; cvt_pk on read. B: bf16 16 KB/buf from packed image,
//    linear reads. Per phase: BAR; STAGE(t+1) 4 glds/wave; vmcnt(4); BAR; COMPUTE(t).
__global__ __launch_bounds__(512, 2) void gemm_mfma_v17(
    const float* __restrict__ latents, const float* __restrict__ boot,
    const char* __restrict__ Wimg, float* __restrict__ P, size_t Pstride,
    int NR, int R, int D, int split, int nMt, int nwg8)
{
    __shared__ __align__(16) char ldsA[2][16384];
    __shared__ __align__(16) char ldsB[2][16384];

    const int tid  = threadIdx.x;
    const int wave = tid >> 6, lane = tid & 63;
    const int l31  = lane & 31, lhi = lane >> 5;
    const int mw   = wave & 1, nw = wave >> 1;   // M half (64 rows), N quarter (64 cols)
    const int KQ   = D / split;
    const int NT   = KQ >> 5;                    // phases of BK=32 (even)

    // XCD swizzle (nwg % 8 == 0 -> bijective); kq-major
    int bid  = blockIdx.x;
    int work = (bid & 7) * nwg8 + (bid >> 3);
    const int kq = work / nMt;
    const int mt = work - kq * nMt;
    const int row0 = mt * 128;
    float* __restrict__ Pq = P + (size_t)kq * Pstride;

    // R = nMt*128 and NR = 128*128: each block purely latents or boot.
    const float* Abase = (row0 < NR) ? latents + (size_t)row0 * D
                                     : boot + (size_t)(row0 - NR) * D;

    // A staging: instr j (0,1): row_loc = wave*16 + j*8 + (lane>>3), unit u' = lane&7;
    // source unit = u' ^ (row_loc & 7). One instr = 8 rows x 128 B = 16 full lines.
    const int au  = lane & 7;
    const int rl0 = (wave << 4) + 0 + (lane >> 3);
    const int rl1 = (wave << 4) + 8 + (lane >> 3);
    const float* asrc0 = Abase + (size_t)rl0 * D + kq * KQ + ((au ^ (rl0 & 7)) << 2);
    const float* asrc1 = Abase + (size_t)rl1 * D + kq * KQ + ((au ^ (rl1 & 7)) << 2);
    const int adst0 = (wave << 11) + 0    + (lane << 4);   // linear per wave
    const int adst1 = (wave << 11) + 1024 + (lane << 4);

    const char* bsrc = Wimg + ((size_t)kq * NT) * 16384 + (wave << 11) + (lane << 4);
    const int bdst0 = (wave << 11) + (lane << 4);

    f32x16 acc[2][2];
    #pragma unroll
    for (int rg = 0; rg < 2; ++rg)
        #pragma unroll
        for (int cg = 0; cg < 2; ++cg)
            #pragma unroll
            for (int r = 0; r < 16; ++r) acc[rg][cg][r] = 0.f;

    // A read: rows r0 = mw*64 + l31, r1 = r0 + 32 (same &7); per ks: units u0, u0+1
    const int ar0 = mw * 64 + l31;
    const int ar1 = ar0 + 32;
    const int ax  = ar0 & 7;
    // B read byte: (ks*2+lhi)*4096 + (nw*64 + l31)*16 + cg*512
    const int boff = (lhi << 12) + ((nw * 64 + l31) << 4);

#define STAGE(T, BUF) do {                                                  \
        const size_t ko_ = (size_t)(T) * 32;                                \
        glds16(asrc0 + ko_, &ldsA[BUF][adst0]);                             \
        glds16(asrc1 + ko_, &ldsA[BUF][adst1]);                             \
        const char* bs_ = bsrc + (size_t)(T) * 16384;                       \
        glds16(bs_,        &ldsB[BUF][bdst0]);                              \
        glds16(bs_ + 1024, &ldsB[BUF][bdst0 + 1024]);                       \
    } while (0)

#define COMPUTE(BUF) do {                                                   \
        _Pragma("unroll")                                                   \
        for (int ks = 0; ks < 2; ++ks) {                                    \
            const int u0_ = ks * 4 + lhi * 2;                               \
            float4 f0_ = *(const float4*)(&ldsA[BUF][ar0 * 128 + ((u0_       ^ ax) << 4)]); \
            float4 f1_ = *(const float4*)(&ldsA[BUF][ar0 * 128 + (((u0_ + 1) ^ ax) << 4)]); \
            float4 g0_ = *(const float4*)(&ldsA[BUF][ar1 * 128 + ((u0_       ^ ax) << 4)]); \
            float4 g1_ = *(const float4*)(&ldsA[BUF][ar1 * 128 + (((u0_ + 1) ^ ax) << 4)]); \
            short8 a0_ = mk8(pkbf(f0_.x, f0_.y), pkbf(f0_.z, f0_.w),        \
                             pkbf(f1_.x, f1_.y), pkbf(f1_.z, f1_.w));       \
            short8 a1_ = mk8(pkbf(g0_.x, g0_.y), pkbf(g0_.z, g0_.w),        \
                             pkbf(g1_.x, g1_.y), pkbf(g1_.z, g1_.w));       \
            short8 b0_ = *(const short8*)(&ldsB[BUF][(ks << 13) + boff]);   \
            short8 b1_ = *(const short8*)(&ldsB[BUF][(ks << 13) + boff + 512]); \
            acc[0][0] = __builtin_amdgcn_mfma_f32_32x32x16_bf16(a0_, b0_, acc[0][0], 0, 0, 0); \
            acc[0][1] = __builtin_amdgcn_mfma_f32_32x32x16_bf16(a0_, b1_, acc[0][1], 0, 0, 0); \
            acc[1][0] = __builtin_amdgcn_mfma_f32_32x32x16_bf16(a1_, b0_, acc[1][0], 0, 0, 0); \
            acc[1][1] = __builtin_amdgcn_mfma_f32_32x32x16_bf16(a1_, b1_, acc[1][1], 0, 0, 0); \
        }                                                                   \
    } while (0)

#define BAR()   __builtin_amdgcn_s_barrier()
#define SCHED() __builtin_amdgcn_sched_barrier(0)
#define WAITV4() asm volatile("s_waitcnt vmcnt(4)" ::: "memory")
#define WAITV0() asm volatile("s_waitcnt vmcnt(0)" ::: "memory")

    STAGE(0, 0);

    int t = 0;
    for (; t + 3 < NT; t += 2) {
        BAR(); SCHED(); STAGE(t + 1, 1); SCHED(); WAITV4(); BAR(); SCHED(); COMPUTE(0);
        BAR(); SCHED(); STAGE(t + 2, 0); SCHED(); WAITV4(); BAR(); SCHED(); COMPUTE(1);
    }
    BAR(); SCHED(); STAGE(NT - 1, 1); SCHED(); WAITV4(); BAR(); SCHED(); COMPUTE(0);
    BAR(); SCHED(); WAITV0(); BAR(); SCHED(); COMPUTE(1);

#undef STAGE
#undef COMPUTE
#undef BAR
#undef SCHED
#undef WAITV4
#undef WAITV0

    // epilogue: raw partials. C layout: col=lane&31, row=(r&3)+8*(r>>2)+4*lhi
    #pragma unroll
    for (int rg = 0; rg < 2; ++rg) {
        #pragma unroll
        for (int cg = 0; cg < 2; ++cg) {
            int col = nw * 64 + cg * 32 + l31;
            if (col < NBINS) {
                #pragma unroll
                for (int r = 0; r < 16; ++r) {
                    int row = row0 + mw * 64 + rg * 32 + (r & 3) + 8 * (r >> 2) + 4 * lhi;
                    Pq[(size_t)row * 256 + col] = acc[rg][cg][r];
                }
            }
        }
    }
}

// softmax over l = sum_q P_q + bias: value, logZ per row
__global__ __launch_bounds__(256) void softmax_statsN(
    const float* __restrict__ P, size_t Pstride, int split,
    const float* __restrict__ bvec, float* __restrict__ values,
    float* __restrict__ logZ, int R)
{
    int row  = blockIdx.x * 4 + (threadIdx.x >> 6);
    int lane = threadIdx.x & 63;
    if (row >= R) return;
    const float* pr = P + (size_t)row * 256;
    const float step = (float)(40.0 / 254.0);

    float l[4];
    float m = -INFINITY;
    #pragma unroll
    for (int u = 0; u < 4; ++u) {
        int idx = lane + 64 * u;
        if (idx < NBINS) {
            float s = bvec[idx];
            for (int q = 0; q < split; ++q) s += pr[(size_t)q * Pstride + idx];
            l[u] = s;
        } else l[u] = -INFINITY;
        m = fmaxf(m, l[u]);
    }
    #pragma unroll
    for (int sh = 32; sh >= 1; sh >>= 1) m = fmaxf(m, __shfl_xor(m, sh, 64));

    float s = 0.f, sc = 0.f;
    #pragma unroll
    for (int u = 0; u < 4; ++u) {
        int idx = lane + 64 * u;
        if (idx < NBINS) {
            float e = __expf(l[u] - m);
            s  += e;
            sc += e * (BIN_LO_F + step * (float)idx);
        }
    }
    #pragma unroll
    for (int sh = 32; sh >= 1; sh >>= 1) {
        s  += __shfl_xor(s, sh, 64);
        sc += __shfl_xor(sc, sh, 64);
    }
    if (lane == 0) {
        values[row] = sc / s;
        logZ[row]   = m + __logf(s);
    }
}

__global__ void lambda_returns_k(
    const float* __restrict__ rewards, const float* __restrict__ dones,
    const float* __restrict__ values, float* __restrict__ returns,
    int B, int H, int NR)
{
    int b = blockIdx.x * blockDim.x + threadIdx.x;
    if (b >= B) return;
    const float gamma = 0.997f;
    const float lam   = 0.95f;
    const float oml   = (float)(1.0 - 0.95);
    float bootv = values[NR + b];
    float g = bootv;
    for (int h = H - 1; h >= 0; --h) {
        float nv   = (h == H - 1) ? bootv : values[b * H + h + 1];
        float mask = 1.0f - dones[b * H + h];
        g = rewards[b * H + h] + gamma * mask * (oml * nv + lam * g);
        returns[b * H + h] = g;
    }
}

__global__ __launch_bounds__(256) void loss_momentsN(
    const float* __restrict__ P, size_t Pstride, int split,
    const float* __restrict__ bvec, const float* __restrict__ logZ,
    const float* __restrict__ values, const float* __restrict__ returns,
    double* __restrict__ accum, int NR)
{
    int row = blockIdx.x * blockDim.x + threadIdx.x;
    double lsum = 0, vsum = 0, v2 = 0, rsum = 0, r2 = 0;
    if (row < NR) {
        float v   = values[row];
        float ret = returns[row];
        float cl  = fminf(fmaxf(ret, BIN_LO_F), BIN_HI_F);
        const float step = (float)(40.0 / 254.0);
        float pos = (cl - BIN_LO_F) / step;
        int low = (int)floorf(pos);
        low = min(max(low, 0), NBINS - 2);
        float frac = pos - (float)low;
        size_t base = (size_t)row * 256;
        float llo = bvec[low], lhi = bvec[low + 1];
        for (int q = 0; q < split; ++q) {
            llo += P[(size_t)q * Pstride + base + low];
            lhi += P[(size_t)q * Pstride + base + low + 1];
        }
        float loss = logZ[row] - (1.f - frac) * llo - frac * lhi;
        lsum = (double)loss;
        vsum = (double)v;   v2 = (double)v * (double)v;
        rsum = (double)ret; r2 = (double)ret * (double)ret;
    }
    lsum = wave_reduce_sum_d(lsum);
    vsum = wave_reduce_sum_d(vsum);
    v2   = wave_reduce_sum_d(v2);
    rsum = wave_reduce_sum_d(rsum);
    r2   = wave_reduce_sum_d(r2);
    if ((threadIdx.x & 63) == 0) {
        atomicAdd(&accum[0], lsum);
        atomicAdd(&accum[1], vsum);
        atomicAdd(&accum[2], v2);
        atomicAdd(&accum[3], rsum);
        atomicAdd(&accum[4], r2);
    }
}

__global__ void finalize_k(const double* __restrict__ accum,
                           float* __restrict__ out, int NR)
{
    if (threadIdx.x == 0 && blockIdx.x == 0) {
        double n  = (double)NR;
        double vl = accum[0] / n;
        double mv = accum[1] / n;
        double vv = (accum[2] - n * mv * mv) / (n - 1.0);
        double mr = accum[3] / n;
        double vr = (accum[4] - n * mr * mr) / (n - 1.0);
        out[0] = (float)(0.5 * vl);
        out[1] = (float)vl;
        out[2] = (float)mv;
        out[3] = (float)mr;
        out[4] = (float)sqrt(vv > 0.0 ? vv : 0.0);
        out[5] = (float)sqrt(vr > 0.0 ? vr : 0.0);
    }
}

extern "C" void kernel_launch(void* const* d_in, const int* in_sizes, int n_in,
                              void* d_out, int out_size, void* d_ws, size_t ws_size,
                              hipStream_t stream) {
    const float* latents = (const float*)d_in[0];
    const float* rewards = (const float*)d_in[1];
    const float* dones   = (const float*)d_in[2];
    const float* boot    = (const float*)d_in[3];
    const float* W       = (const float*)d_in[4];
    const float* bvec    = (const float*)d_in[5];
    float* out = (float*)d_out;

    const int BH = in_sizes[1];          // B*H = 16384
    const int D  = in_sizes[0] / BH;     // 4096
    const int B  = in_sizes[3] / D;      // 1024
    const int H  = BH / B;               // 16
    const int NR = BH;
    const int R  = NR + B;               // 17408 = 136 * 128

    const size_t Pstride = (size_t)R * 256;
    const size_t fixed   = (size_t)R * 2 * 4 + (size_t)NR * 4 + 512 +
                           (size_t)(D / 32) * 16384 + 4096;
    int split = (ws_size >= 4 * Pstride * 4 + fixed) ? 4 : 2;

    char* ws = (char*)d_ws;
    size_t off = 0;
    float* P = (float*)(ws + off); off += (size_t)split * Pstride * sizeof(float);
    float* values = (float*)(ws + off); off += (size_t)R * sizeof(float);
    float* logZ   = (float*)(ws + off); off += (size_t)R * sizeof(float);
    float* rets   = (float*)(ws + off); off += (size_t)NR * sizeof(float);
    off = (off + 255) & ~(size_t)255;
    double* accum = (double*)(ws + off); off += 64;
    off = (off + 255) & ~(size_t)255;
    char* Wimg    = ws + off; off += (size_t)(D / 32) * 16384;   // 2 MB

    hipMemsetAsync(accum, 0, 64, stream);

    const int packUnits = (D / 32) * 1024;           // 16B units
    pack_w7<<<packUnits / 256, 256, 0, stream>>>(W, Wimg);

    const int nMt = R / 128;                         // 136
    const int nwg = nMt * split;                     // 544 or 272
    gemm_mfma_v17<<<nwg, 512, 0, stream>>>(latents, boot, Wimg, P, Pstride,
                                           NR, R, D, split, nMt, nwg / 8);
    softmax_statsN<<<(R + 3) / 4, 256, 0, stream>>>(P, Pstride, split, bvec,
                                                    values, logZ, R);
    lambda_returns_k<<<(B + 255) / 256, 256, 0, stream>>>(rewards, dones, values, rets, B, H, NR);
    loss_momentsN<<<(NR + 255) / 256, 256, 0, stream>>>(P, Pstride, split, bvec, logZ,
                                                        values, rets, accum, NR);
    finalize_k<<<1, 64, 0, stream>>>(accum, out, NR);
}